// Round 1
// baseline (274.017 us; speedup 1.0000x reference)
//
#include <hip/hip_runtime.h>
#include <hip/hip_cooperative_groups.h>
#include <math.h>

namespace cg = cooperative_groups;

#define AN 4096
#define CN 8
#define FN 64
#define ACN (AN*CN)   // 32768

typedef __attribute__((ext_vector_type(8))) short bf16x8;
typedef __attribute__((ext_vector_type(4))) float f32x4;

__device__ inline unsigned short f2bf(float f) {
    unsigned u = __float_as_uint(f);
    unsigned r = ((u >> 16) & 1) + 0x7FFFu;   // round-to-nearest-even
    return (unsigned short)((u + r) >> 16);
}

// ---------------------------------------------------------------------------
// Phase 1: normalize. Writes xnb bf16 [c][a][f] (MFMA operand) and inv[a*8+c]
// (fp32 inverse norm; phase 3 recomputes xn = x*inv exactly as before —
// same multiply, same rounding). The fp32 xn array is gone: -8MB write.
// 512 blocks x 64 rows each.
// ---------------------------------------------------------------------------
__device__ inline void phase1_normalize(const float* __restrict__ x,
                                        unsigned short* __restrict__ xnb,
                                        float* __restrict__ inv,
                                        int blk, int tid)
{
    int grp  = tid >> 4;
    int slot = tid & 15;
    #pragma unroll
    for (int s = 0; s < 4; ++s) {
        int V = blk * 64 + s * 16 + grp;          // 0..32767 = a*8+c
        const float4 v = *(const float4*)(x + (size_t)V * FN + slot * 4);
        float ss = v.x*v.x + v.y*v.y + v.z*v.z + v.w*v.w;
        ss += __shfl_xor(ss, 1);
        ss += __shfl_xor(ss, 2);
        ss += __shfl_xor(ss, 4);
        ss += __shfl_xor(ss, 8);
        float sc = 1.0f / fmaxf(sqrtf(ss), 1e-6f);
        int a = V >> 3, c = V & 7;
        ushort4 ob;
        ob.x = f2bf(v.x * sc); ob.y = f2bf(v.y * sc);
        ob.z = f2bf(v.z * sc); ob.w = f2bf(v.w * sc);
        *(ushort4*)(xnb + ((size_t)c * AN + a) * FN + slot * 4) = ob;
        if (slot == 0) inv[V] = sc;
    }
}

// ---------------------------------------------------------------------------
// Phase 2: MFMA sim + in-register packed argmax (unchanged structure; the
// diagonal exclusion is hoisted into a wave-uniform branch so 15/16 fragments
// pay zero VALU for it).
// ---------------------------------------------------------------------------
__device__ inline void phase2_argmax(const unsigned short* __restrict__ xnb,
                                     unsigned int* __restrict__ pP,
                                     uint4* lds4, int blk, int tid)
{
    int half = blk & 1;
    int rt   = (blk >> 1) & 31;
    int c    = blk >> 6;
    int a0   = rt * 128;
    int b0base = half * 2048;

    const uint4* __restrict__ Xc4 = (const uint4*)(xnb + (size_t)c * AN * FN);

    int lane = tid & 63;
    int w    = tid >> 6;
    int wr   = w >> 1;
    int wc   = w & 1;
    int l15  = lane & 15;
    int quad = lane >> 4;

    int srow   = tid >> 3;
    int schunk = tid & 7;

    // ---- stage A tile ----
    #pragma unroll
    for (int s = 0; s < 4; ++s) {
        int r = srow + 32 * s;
        lds4[r * 8 + (schunk ^ (r & 7))] = Xc4[(size_t)(a0 + r) * 8 + schunk];
    }
    // ---- stage B tile 0 ----
    #pragma unroll
    for (int s = 0; s < 4; ++s) {
        int r = srow + 32 * s;
        lds4[1024 + r * 8 + (schunk ^ (r & 7))] = Xc4[(size_t)(b0base + r) * 8 + schunk];
    }
    __syncthreads();

    // ---- A fragments into registers ----
    bf16x8 afr[4][2];
    #pragma unroll
    for (int mi = 0; mi < 4; ++mi)
        #pragma unroll
        for (int ks = 0; ks < 2; ++ks) {
            int r  = wr * 64 + mi * 16 + l15;
            int ch = (ks * 4 + quad) ^ (r & 7);
            afr[mi][ks] = ((const bf16x8*)lds4)[r * 8 + ch];
        }

    float bestp[16];
    #pragma unroll
    for (int i = 0; i < 16; ++i) bestp[i] = 0.0f;

    const f32x4 two = {2.0f, 2.0f, 2.0f, 2.0f};

    for (int it = 0; it < 16; ++it) {
        int cur = it & 1;
        uint4 gv[4];
        if (it < 15) {
            int g0 = b0base + (it + 1) * 128;
            #pragma unroll
            for (int s = 0; s < 4; ++s)
                gv[s] = Xc4[(size_t)(g0 + srow + 32 * s) * 8 + schunk];
        }

        f32x4 acc[4][4];
        const bf16x8* bt = (const bf16x8*)(lds4 + 1024 + cur * 1024);
        #pragma unroll
        for (int ks = 0; ks < 2; ++ks) {
            #pragma unroll
            for (int ni = 0; ni < 4; ++ni) {
                int r  = wc * 64 + ni * 16 + l15;
                int ch = (ks * 4 + quad) ^ (r & 7);
                bf16x8 bfr = bt[r * 8 + ch];
                #pragma unroll
                for (int mi = 0; mi < 4; ++mi)
                    acc[mi][ni] = __builtin_amdgcn_mfma_f32_16x16x32_bf16(
                        afr[mi][ks], bfr, (ks == 0) ? two : acc[mi][ni], 0, 0, 0);
            }
        }

        int colblk = b0base + it * 128 + wc * 64;
        #pragma unroll
        for (int ni = 0; ni < 4; ++ni) {
            int cfrag = colblk + ni * 16;
            unsigned code = (unsigned)(cfrag + l15);
            #pragma unroll
            for (int mi = 0; mi < 4; ++mi) {
                int rfrag = a0 + wr * 64 + mi * 16;
                unsigned pbv[4];
                #pragma unroll
                for (int r = 0; r < 4; ++r)
                    pbv[r] = (__float_as_uint(acc[mi][ni][r]) & 0xFFFFF000u) | code;
                if (rfrag == cfrag) {               // wave-uniform -> s_cbranch
                    #pragma unroll
                    for (int r = 0; r < 4; ++r)
                        if (l15 == quad * 4 + r) pbv[r] = 0u;
                }
                #pragma unroll
                for (int r = 0; r < 4; ++r)
                    bestp[mi * 4 + r] = fmaxf(bestp[mi * 4 + r], __uint_as_float(pbv[r]));
            }
        }

        if (it < 15) {
            #pragma unroll
            for (int s = 0; s < 4; ++s) {
                int r = srow + 32 * s;
                lds4[1024 + (cur ^ 1) * 1024 + r * 8 + (schunk ^ (r & 7))] = gv[s];
            }
        }
        __syncthreads();
    }

    // ---- reduce across the 16 column-lanes ----
    #pragma unroll
    for (int i = 0; i < 16; ++i) {
        float v = bestp[i];
        v = fmaxf(v, __shfl_xor(v, 1));
        v = fmaxf(v, __shfl_xor(v, 2));
        v = fmaxf(v, __shfl_xor(v, 4));
        v = fmaxf(v, __shfl_xor(v, 8));
        bestp[i] = v;
    }
    __syncthreads();
    float* red = (float*)lds4;
    if (l15 == 0) {
        #pragma unroll
        for (int mi = 0; mi < 4; ++mi)
            #pragma unroll
            for (int r = 0; r < 4; ++r)
                red[w * 64 + mi * 16 + quad * 4 + r] = bestp[mi * 4 + r];
    }
    __syncthreads();
    if (tid < 128) {
        int wr2 = tid >> 6, r64 = tid & 63;
        float p = fmaxf(red[(2 * wr2) * 64 + r64], red[(2 * wr2 + 1) * 64 + r64]);
        int a = a0 + tid;
        pP[(size_t)half * ACN + (size_t)a * CN + c] = __float_as_uint(p);
    }
}

// ---------------------------------------------------------------------------
// Phase 3: merge halves, unpack index, exact fp32 distance (x*inv recomputes
// the old xn values with identical multiplies) + log, block-reduce.
// ---------------------------------------------------------------------------
__device__ inline void phase3_dist(const float* __restrict__ x,
                                   const float* __restrict__ inv,
                                   const unsigned int* __restrict__ pP,
                                   float* __restrict__ partials,
                                   int blk, int tid, float* sharedf)
{
    if (blk >= 128) return;
    int id = blk * 256 + tid;                   // a*8 + c
    float p0 = __uint_as_float(pP[id]);
    float p1 = __uint_as_float(pP[ACN + id]);
    unsigned pm = __float_as_uint(fmaxf(p0, p1));
    int m = (int)(pm & 0xFFFu);
    int c = id & 7;
    int idb = m * CN + c;
    float sa = inv[id];
    float sb = inv[idb];
    const float* xa = x + (size_t)id  * FN;
    const float* xb = x + (size_t)idb * FN;
    float ss = 0.0f;
    #pragma unroll
    for (int q = 0; q < 16; ++q) {
        float4 va = *(const float4*)(xa + 4 * q);
        float4 vb = *(const float4*)(xb + 4 * q);
        float d0 = va.x * sa - vb.x * sb + 1e-6f;
        float d1 = va.y * sa - vb.y * sb + 1e-6f;
        float d2 = va.z * sa - vb.z * sb + 1e-6f;
        float d3 = va.w * sa - vb.w * sb + 1e-6f;
        ss += d0*d0 + d1*d1 + d2*d2 + d3*d3;
    }
    float t = logf(sqrtf(ss) + 1e-6f);
    #pragma unroll
    for (int off = 32; off > 0; off >>= 1) t += __shfl_down(t, off);
    if ((tid & 63) == 0) sharedf[tid >> 6] = t;
    __syncthreads();
    if (tid == 0)
        partials[blk] = sharedf[0] + sharedf[1] + sharedf[2] + sharedf[3];
}

// ---------------------------------------------------------------------------
// Fused cooperative kernel: 512 blocks x 256 threads, 2 blocks/CU
// (LDS 48KB, VGPR capped by launch_bounds(256,2)) — co-resident by
// construction, grid.sync() replaces 3 kernel-launch gaps.
// ---------------------------------------------------------------------------
__global__ __launch_bounds__(256, 2) void k_fused(const float* __restrict__ x,
                                                  unsigned short* __restrict__ xnb,
                                                  float* __restrict__ inv,
                                                  unsigned int* __restrict__ pP,
                                                  float* __restrict__ partials,
                                                  float* __restrict__ out)
{
    __shared__ uint4 lds4[3 * 1024];
    int tid = threadIdx.x;
    int blk = blockIdx.x;
    cg::grid_group g = cg::this_grid();

    phase1_normalize(x, xnb, inv, blk, tid);
    g.sync();
    phase2_argmax(xnb, pP, lds4, blk, tid);
    g.sync();
    phase3_dist(x, inv, pP, partials, blk, tid, (float*)lds4);
    g.sync();
    if (blk == 0 && tid < 64) {
        float v = partials[tid] + partials[tid + 64];
        #pragma unroll
        for (int off = 32; off > 0; off >>= 1) v += __shfl_down(v, off);
        if (tid == 0) out[0] = -v / (float)ACN;
    }
}

// ---------------------------------------------------------------------------
// Fallback path (non-cooperative), same phase bodies.
// ---------------------------------------------------------------------------
__global__ __launch_bounds__(256) void k1s(const float* __restrict__ x,
                                           unsigned short* __restrict__ xnb,
                                           float* __restrict__ inv)
{
    phase1_normalize(x, xnb, inv, blockIdx.x, threadIdx.x);
}

__global__ __launch_bounds__(256, 2) void k2s(const unsigned short* __restrict__ xnb,
                                              unsigned int* __restrict__ pP)
{
    __shared__ uint4 lds4[3 * 1024];
    phase2_argmax(xnb, pP, lds4, blockIdx.x, threadIdx.x);
}

__global__ __launch_bounds__(256) void k3s(const float* __restrict__ x,
                                           const float* __restrict__ inv,
                                           const unsigned int* __restrict__ pP,
                                           float* __restrict__ partials)
{
    __shared__ float sharedf[4];
    phase3_dist(x, inv, pP, partials, blockIdx.x, threadIdx.x, sharedf);
}

__global__ __launch_bounds__(64) void k4s(const float* __restrict__ partials,
                                          float* __restrict__ out)
{
    int t = threadIdx.x;
    float v = partials[t] + partials[t + 64];
    #pragma unroll
    for (int off = 32; off > 0; off >>= 1) v += __shfl_down(v, off);
    if (t == 0) out[0] = -v / (float)ACN;
}

extern "C" void kernel_launch(void* const* d_in, const int* in_sizes, int n_in,
                              void* d_out, int out_size, void* d_ws, size_t ws_size,
                              hipStream_t stream)
{
    const float* x = (const float*)d_in[0];
    unsigned short* xnb = (unsigned short*)d_ws;               // 4 MB bf16 [c][a][f]
    float* inv = (float*)(xnb + (size_t)AN * CN * FN);         // 128 KB inverse norms
    unsigned int* pP = (unsigned int*)(inv + ACN);             // 256 KB packed argmax
    float* partials = (float*)(pP + 2 * ACN);                  // 512 B
    float* outf = (float*)d_out;

    void* args[6];
    args[0] = (void*)&x;
    args[1] = (void*)&xnb;
    args[2] = (void*)&inv;
    args[3] = (void*)&pP;
    args[4] = (void*)&partials;
    args[5] = (void*)&outf;

    hipError_t err = hipLaunchCooperativeKernel((const void*)k_fused,
                                                dim3(512), dim3(256),
                                                args, 0, stream);
    if (err != hipSuccess) {
        // Fallback: proven 4-dispatch pipeline.
        k1s<<<512, 256, 0, stream>>>(x, xnb, inv);
        k2s<<<512, 256, 0, stream>>>(xnb, pP);
        k3s<<<128, 256, 0, stream>>>(x, inv, pP, partials);
        k4s<<<1, 64, 0, stream>>>(partials, outf);
    }
}

// Round 2
// 91.916 us; speedup vs baseline: 2.9812x; 2.9812x over previous
//
#include <hip/hip_runtime.h>
#include <math.h>

#define AN 4096
#define CN 8
#define FN 64
#define ACN (AN*CN)   // 32768

typedef __attribute__((ext_vector_type(8))) short bf16x8;
typedef __attribute__((ext_vector_type(4))) float f32x4;

__device__ inline unsigned short f2bf(float f) {
    unsigned u = __float_as_uint(f);
    unsigned r = ((u >> 16) & 1) + 0x7FFFu;   // round-to-nearest-even
    return (unsigned short)((u + r) >> 16);
}

// ---------------------------------------------------------------------------
// K1: normalize -> xnb bf16 [c][a][f] (MFMA operand) + inv[a*8+c] fp32
// inverse norms. No fp32 xn array: k3 recomputes x*inv (identical multiply,
// identical rounding — verified bit-exact in round 1). 512 blocks x 64 rows.
// ---------------------------------------------------------------------------
__global__ __launch_bounds__(256) void k1_normalize(const float* __restrict__ x,
                                                    unsigned short* __restrict__ xnb,
                                                    float* __restrict__ inv)
{
    int tid  = threadIdx.x;
    int grp  = tid >> 4;
    int slot = tid & 15;
    #pragma unroll
    for (int s = 0; s < 4; ++s) {
        int V = blockIdx.x * 64 + s * 16 + grp;      // 0..32767 = a*8+c
        const float4 v = *(const float4*)(x + (size_t)V * FN + slot * 4);
        float ss = v.x*v.x + v.y*v.y + v.z*v.z + v.w*v.w;
        ss += __shfl_xor(ss, 1);
        ss += __shfl_xor(ss, 2);
        ss += __shfl_xor(ss, 4);
        ss += __shfl_xor(ss, 8);
        float sc = 1.0f / fmaxf(sqrtf(ss), 1e-6f);
        int a = V >> 3, c = V & 7;
        ushort4 ob;
        ob.x = f2bf(v.x * sc); ob.y = f2bf(v.y * sc);
        ob.z = f2bf(v.z * sc); ob.w = f2bf(v.w * sc);
        *(ushort4*)(xnb + ((size_t)c * AN + a) * FN + slot * 4) = ob;
        if (slot == 0) inv[V] = sc;
    }
}

// ---------------------------------------------------------------------------
// K2: MFMA sim + in-register packed argmax.
// Grid 512 = 8 channels x 32 row-tiles x 2 col-halves. 256 threads = 4 waves
// in 2x2 quadrants. Tile: 128 rows x 128 cols x K=64 per col-iter, 16 iters.
// A-frags register-resident; B double-buffered in LDS, 16B chunks XOR-swizzled
// by (row&7) -> <=2-way bank alias (free, m136).
// Packed argmax: acc init 2.0 (s'=2+sim in [1,3]); packed=(bits&~0xFFF)|col;
// float-max == lexicographic (quantized s', col). Diagonal excluded by zeroing
// the packed candidate on the diag fragment (wave-uniform branch).
// Argmax update restructured: gather 4 candidates per (mi,r) then reduce via
// fmax chain -> clang emits v_and_or_b32 packs + 2x v_max3_f32 (6 VALU per
// 4 candidates vs 8-12 in the serial-chain form).
// ---------------------------------------------------------------------------
__global__ __launch_bounds__(256, 2) void k2_argmax(const unsigned short* __restrict__ xnb,
                                                    unsigned int* __restrict__ pP)
{
    __shared__ uint4 lds4[3 * 1024];   // At [0,1024) | Bt0 [1024,2048) | Bt1 [2048,3072)

    int blk  = blockIdx.x;
    int half = blk & 1;
    int rt   = (blk >> 1) & 31;
    int c    = blk >> 6;
    int a0   = rt * 128;
    int b0base = half * 2048;

    const uint4* __restrict__ Xc4 = (const uint4*)(xnb + (size_t)c * AN * FN);

    int tid  = threadIdx.x;
    int lane = tid & 63;
    int w    = tid >> 6;
    int wr   = w >> 1;        // row quadrant 0..1
    int wc   = w & 1;         // col quadrant 0..1
    int l15  = lane & 15;
    int quad = lane >> 4;

    int srow   = tid >> 3;    // staging row base 0..31
    int schunk = tid & 7;     // staging 16B chunk 0..7

    // ---- stage A tile ----
    #pragma unroll
    for (int s = 0; s < 4; ++s) {
        int r = srow + 32 * s;
        lds4[r * 8 + (schunk ^ (r & 7))] = Xc4[(size_t)(a0 + r) * 8 + schunk];
    }
    // ---- stage B tile 0 ----
    #pragma unroll
    for (int s = 0; s < 4; ++s) {
        int r = srow + 32 * s;
        lds4[1024 + r * 8 + (schunk ^ (r & 7))] = Xc4[(size_t)(b0base + r) * 8 + schunk];
    }
    __syncthreads();

    // ---- A fragments into registers (loop-invariant) ----
    bf16x8 afr[4][2];
    #pragma unroll
    for (int mi = 0; mi < 4; ++mi)
        #pragma unroll
        for (int ks = 0; ks < 2; ++ks) {
            int r  = wr * 64 + mi * 16 + l15;
            int ch = (ks * 4 + quad) ^ (r & 7);
            afr[mi][ks] = ((const bf16x8*)lds4)[r * 8 + ch];
        }

    float bestp[16];
    #pragma unroll
    for (int i = 0; i < 16; ++i) bestp[i] = 0.0f;

    const f32x4 two = {2.0f, 2.0f, 2.0f, 2.0f};

    for (int it = 0; it < 16; ++it) {
        int cur = it & 1;
        // prefetch next B tile into registers
        uint4 gv[4];
        if (it < 15) {
            int g0 = b0base + (it + 1) * 128;
            #pragma unroll
            for (int s = 0; s < 4; ++s)
                gv[s] = Xc4[(size_t)(g0 + srow + 32 * s) * 8 + schunk];
        }

        // ---- MFMA on buffer cur ----
        f32x4 acc[4][4];
        const bf16x8* bt = (const bf16x8*)(lds4 + 1024 + cur * 1024);
        #pragma unroll
        for (int ks = 0; ks < 2; ++ks) {
            #pragma unroll
            for (int ni = 0; ni < 4; ++ni) {
                int r  = wc * 64 + ni * 16 + l15;
                int ch = (ks * 4 + quad) ^ (r & 7);
                bf16x8 bfr = bt[r * 8 + ch];
                #pragma unroll
                for (int mi = 0; mi < 4; ++mi)
                    acc[mi][ni] = __builtin_amdgcn_mfma_f32_16x16x32_bf16(
                        afr[mi][ks], bfr, (ks == 0) ? two : acc[mi][ni], 0, 0, 0);
            }
        }

        // ---- packed argmax update (gather-4 then max3-reduce) ----
        int colblk = b0base + it * 128 + wc * 64;
        int codebase = colblk + l15;
        #pragma unroll
        for (int mi = 0; mi < 4; ++mi) {
            int rfrag = a0 + wr * 64 + mi * 16;
            #pragma unroll
            for (int r = 0; r < 4; ++r) {
                float cand[4];
                #pragma unroll
                for (int ni = 0; ni < 4; ++ni) {
                    unsigned pb = (__float_as_uint(acc[mi][ni][r]) & 0xFFFFF000u)
                                | (unsigned)(codebase + ni * 16);
                    cand[ni] = __uint_as_float(pb);
                }
                #pragma unroll
                for (int ni = 0; ni < 4; ++ni) {
                    if (rfrag == colblk + ni * 16) {         // wave-uniform
                        if (l15 == quad * 4 + r) cand[ni] = 0.0f;
                    }
                }
                int bi = mi * 4 + r;
                bestp[bi] = fmaxf(fmaxf(fmaxf(fmaxf(cand[0], cand[1]), cand[2]),
                                        cand[3]), bestp[bi]);
            }
        }

        // ---- write prefetched tile into other buffer ----
        if (it < 15) {
            #pragma unroll
            for (int s = 0; s < 4; ++s) {
                int r = srow + 32 * s;
                lds4[1024 + (cur ^ 1) * 1024 + r * 8 + (schunk ^ (r & 7))] = gv[s];
            }
        }
        __syncthreads();
    }

    // ---- reduce across the 16 column-lanes ----
    #pragma unroll
    for (int i = 0; i < 16; ++i) {
        float v = bestp[i];
        v = fmaxf(v, __shfl_xor(v, 1));
        v = fmaxf(v, __shfl_xor(v, 2));
        v = fmaxf(v, __shfl_xor(v, 4));
        v = fmaxf(v, __shfl_xor(v, 8));
        bestp[i] = v;
    }
    __syncthreads();                    // At region now reusable
    float* red = (float*)lds4;          // red[w][64]
    if (l15 == 0) {
        #pragma unroll
        for (int mi = 0; mi < 4; ++mi)
            #pragma unroll
            for (int r = 0; r < 4; ++r)
                red[w * 64 + mi * 16 + quad * 4 + r] = bestp[mi * 4 + r];
    }
    __syncthreads();
    if (tid < 128) {
        int wr2 = tid >> 6, r64 = tid & 63;
        float p = fmaxf(red[(2 * wr2) * 64 + r64], red[(2 * wr2 + 1) * 64 + r64]);
        int a = a0 + tid;
        pP[(size_t)half * ACN + (size_t)a * CN + c] = __float_as_uint(p);
    }
}

// ---------------------------------------------------------------------------
// K3: merge halves, unpack index, exact fp32 distance (x*inv recomputes the
// normalized values with identical multiplies) + log, block-reduce.
// ---------------------------------------------------------------------------
__global__ __launch_bounds__(256) void k3_dist(const float* __restrict__ x,
                                               const float* __restrict__ inv,
                                               const unsigned int* __restrict__ pP,
                                               float* __restrict__ partials)
{
    int tid = threadIdx.x;
    int id = blockIdx.x * 256 + tid;            // a*8 + c
    float p0 = __uint_as_float(pP[id]);
    float p1 = __uint_as_float(pP[ACN + id]);
    unsigned pm = __float_as_uint(fmaxf(p0, p1));
    int m = (int)(pm & 0xFFFu);
    int c = id & 7;
    int idb = m * CN + c;
    float sa = inv[id];
    float sb = inv[idb];
    const float* xa = x + (size_t)id  * FN;
    const float* xb = x + (size_t)idb * FN;
    float ss = 0.0f;
    #pragma unroll
    for (int q = 0; q < 16; ++q) {
        float4 va = *(const float4*)(xa + 4 * q);
        float4 vb = *(const float4*)(xb + 4 * q);
        float d0 = va.x * sa - vb.x * sb + 1e-6f;
        float d1 = va.y * sa - vb.y * sb + 1e-6f;
        float d2 = va.z * sa - vb.z * sb + 1e-6f;
        float d3 = va.w * sa - vb.w * sb + 1e-6f;
        ss += d0*d0 + d1*d1 + d2*d2 + d3*d3;
    }
    float val = logf(sqrtf(ss) + 1e-6f);

    float t = val;
    #pragma unroll
    for (int off = 32; off > 0; off >>= 1) t += __shfl_down(t, off);
    __shared__ float ws4[4];
    if ((tid & 63) == 0) ws4[tid >> 6] = t;
    __syncthreads();
    if (tid == 0)
        partials[blockIdx.x] = ws4[0] + ws4[1] + ws4[2] + ws4[3];
}

// ---------------------------------------------------------------------------
// K4: out = -sum(partials)/32768
// ---------------------------------------------------------------------------
__global__ __launch_bounds__(64) void k4_final(const float* __restrict__ partials,
                                               float* __restrict__ out)
{
    int t = threadIdx.x;
    float v = partials[t] + partials[t + 64];
    #pragma unroll
    for (int off = 32; off > 0; off >>= 1) v += __shfl_down(v, off);
    if (t == 0) out[0] = -v / (float)ACN;
}

extern "C" void kernel_launch(void* const* d_in, const int* in_sizes, int n_in,
                              void* d_out, int out_size, void* d_ws, size_t ws_size,
                              hipStream_t stream)
{
    const float* x = (const float*)d_in[0];
    unsigned short* xnb = (unsigned short*)d_ws;               // 4 MB bf16 [c][a][f]
    float* inv = (float*)(xnb + (size_t)AN * CN * FN);         // 128 KB inverse norms
    unsigned int* pP = (unsigned int*)(inv + ACN);             // 256 KB packed argmax
    float* partials = (float*)(pP + 2 * ACN);                  // 512 B

    k1_normalize<<<512, 256, 0, stream>>>(x, xnb, inv);
    k2_argmax  <<<512, 256, 0, stream>>>(xnb, pP);
    k3_dist    <<<128, 256, 0, stream>>>(x, inv, pP, partials);
    k4_final   <<<1, 64, 0, stream>>>(partials, (float*)d_out);
}